// Round 3
// baseline (181.740 us; speedup 1.0000x reference)
//
#include <hip/hip_runtime.h>
#include <math.h>

static constexpr int kB  = 16;
static constexpr int kT  = 15;
static constexpr int kH  = 480;
static constexpr int kW  = 640;
static constexpr int kCH = 16;
static constexpr int kP  = 8;
static constexpr int kN  = kB * 16 * 16;   // 4096 sequences
static constexpr float kEPS = 1e-5f;

__device__ __forceinline__ float gelu_exact(float v) {
    return 0.5f * v * (1.0f + erff(v * 0.7071067811865476f));
}

// ---------------------------------------------------------------------------
// K1: 30x40 block-mean downsample. One block per (b,t,i)-strip (30 rows).
// 320 threads: tid -> (rhalf = tid/160, col4 = tid%160); each sums 15 rows of
// one float4 column (rows are 2560B contiguous, fully coalesced). Then 16
// threads reduce 2x10 col-sums each into seq[t][n].
// ---------------------------------------------------------------------------
__global__ __launch_bounds__(320) void k_down(const float* __restrict__ x,
                                              float* __restrict__ seq) {
    int blk = blockIdx.x;          // (b*kT + t)*16 + i
    int i  = blk & 15;
    int bt = blk >> 4;             // b*kT + t
    int t  = bt % kT;
    int b  = bt / kT;
    const float4* src = (const float4*)(x + ((size_t)bt * kH + (size_t)i * 30) * kW);
    __shared__ float colsum[320];
    int tid = threadIdx.x;
    int rhalf = tid / 160;
    int col4  = tid - rhalf * 160;
    const float4* s0 = src + (size_t)(rhalf * 15) * 160 + col4;
    float acc = 0.f;
    #pragma unroll
    for (int r = 0; r < 15; ++r) {
        float4 v = s0[r * 160];
        acc += (v.x + v.y) + (v.z + v.w);
    }
    colsum[tid] = acc;
    __syncthreads();
    if (tid < 16) {
        float s = 0.f;
        #pragma unroll
        for (int j = 0; j < 10; ++j)
            s += colsum[tid * 10 + j] + colsum[160 + tid * 10 + j];
        s *= (1.0f / 1200.0f);
        seq[t * kN + b * 256 + i * 16 + tid] = s;   // [t][n] layout, coalesced K2 reads
    }
}

// ---------------------------------------------------------------------------
// K2: per-sequence SSM scan + last-step MLP head. One thread per sequence.
// LN1 of an affine-in-s input collapses to closed form; Bu[p] collapses to
// r*(s*P1[p]+P0[p])+Pb[p]. Only t=T-1 feeds the output head.
// ---------------------------------------------------------------------------
__global__ __launch_bounds__(64, 1) void k_ssm(
    const float* __restrict__ seq,
    const float* __restrict__ w_in, const float* __restrict__ b_in,
    const float* __restrict__ ln1_g, const float* __restrict__ ln1_b,
    const float* __restrict__ Lam_re, const float* __restrict__ Lam_im,
    const float* __restrict__ Bre, const float* __restrict__ Bim,
    const float* __restrict__ Cre, const float* __restrict__ Cim,
    const float* __restrict__ Dv, const float* __restrict__ log_step,
    const float* __restrict__ ln2_g, const float* __restrict__ ln2_b,
    const float* __restrict__ w_enc, const float* __restrict__ w_dec,
    const float* __restrict__ w_out, const float* __restrict__ b_out,
    float* __restrict__ yd)
{
    const int n = blockIdx.x * 64 + threadIdx.x;   // [0,4096)

    // LN1 closed-form stats
    float av[kCH], dvv[kCH], g1[kCH], b1[kCH];
    float mw = 0.f, mb = 0.f;
    #pragma unroll
    for (int c = 0; c < kCH; ++c) {
        av[c] = w_in[c]; dvv[c] = b_in[c];
        g1[c] = ln1_g[c]; b1[c] = ln1_b[c];
        mw += av[c]; mb += dvv[c];
    }
    mw *= (1.f / kCH); mb *= (1.f / kCH);
    float Saa = 0.f, Sad = 0.f, Sdd = 0.f;
    #pragma unroll
    for (int c = 0; c < kCH; ++c) {
        av[c] -= mw; dvv[c] -= mb;
        Saa += av[c] * av[c];
        Sad += av[c] * dvv[c];
        Sdd += dvv[c] * dvv[c];
    }
    Saa *= (1.f / kCH); Sad *= (1.f / kCH); Sdd *= (1.f / kCH);

    // per-pole discretization + projected input vectors
    float Lbr[kP], Lbi[kP];
    float P1r[kP], P1i[kP], P0r[kP], P0i[kP], Pbr[kP], Pbi[kP];
    float msk[kP];
    #pragma unroll
    for (int p = 0; p < kP; ++p) {
        float st  = expf(log_step[p]);
        float lre = Lam_re[p], lim = Lam_im[p];
        float eL  = expf(lre * st);
        float lbr = eL * cosf(lim * st), lbi = eL * sinf(lim * st);
        Lbr[p] = lbr; Lbi[p] = lbi;
        float inv = 1.f / (lre * lre + lim * lim);
        float nr = lbr - 1.f, ni = lbi;
        float qr = (nr * lre + ni * lim) * inv;    // (Lam_bar-1)/Lam
        float qi = (ni * lre - nr * lim) * inv;
        float s1r = 0.f, s1i = 0.f, s0r = 0.f, s0i = 0.f, sbr = 0.f, sbi = 0.f;
        #pragma unroll
        for (int c = 0; c < kCH; ++c) {
            float br = Bre[p * kCH + c], bi = Bim[p * kCH + c];
            float a1 = av[c]  * g1[c];
            float a0 = dvv[c] * g1[c];
            s1r += a1 * br;   s1i += a1 * bi;
            s0r += a0 * br;   s0i += a0 * bi;
            sbr += b1[c] * br; sbi += b1[c] * bi;
        }
        P1r[p] = qr * s1r - qi * s1i;  P1i[p] = qr * s1i + qi * s1r;
        P0r[p] = qr * s0r - qi * s0i;  P0i[p] = qr * s0i + qi * s0r;
        Pbr[p] = qr * sbr - qi * sbi;  Pbi[p] = qr * sbi + qi * sbr;
        float freq = st * fabsf(lim) * 0.15915494309189535f;  // /(2*pi)
        msk[p] = (freq < 0.25f) ? 1.f : 0.f;
    }

    float xr[kP], xi[kP];
    #pragma unroll
    for (int p = 0; p < kP; ++p) { xr[p] = 0.f; xi[p] = 0.f; }

    float s_last = 0.f, r_last = 0.f;
    for (int t = 0; t < kT; ++t) {
        float s = seq[t * kN + n];
        float var = (s * s) * Saa + 2.f * s * Sad + Sdd;
        float r = rsqrtf(var + kEPS);
        float be = r * s;
        #pragma unroll
        for (int p = 0; p < kP; ++p) {
            float bur = be * P1r[p] + r * P0r[p] + Pbr[p];
            float bui = be * P1i[p] + r * P0i[p] + Pbi[p];
            float nxr = Lbr[p] * xr[p] - Lbi[p] * xi[p] + bur;
            float nxi = Lbr[p] * xi[p] + Lbi[p] * xr[p] + bui;
            xr[p] = nxr; xi[p] = nxi;
        }
        s_last = s; r_last = r;
    }

    // last-step head
    float fx[kCH];
    #pragma unroll
    for (int c = 0; c < kCH; ++c)
        fx[c] = (s_last * av[c] + dvv[c]) * r_last * g1[c] + b1[c];

    float xmr[kP], xmi[kP];
    #pragma unroll
    for (int p = 0; p < kP; ++p) { xmr[p] = xr[p] * msk[p]; xmi[p] = xi[p] * msk[p]; }

    float x1[kCH];
    float m1 = 0.f;
    #pragma unroll
    for (int c = 0; c < kCH; ++c) {
        float ys = fx[c] * Dv[c];
        #pragma unroll
        for (int p = 0; p < kP; ++p)
            ys += xmr[p] * Cre[c * kP + p] - xmi[p] * Cim[c * kP + p];
        x1[c] = gelu_exact(ys) + fx[c];
        m1 += x1[c];
    }
    m1 *= (1.f / kCH);
    float v1 = 0.f;
    #pragma unroll
    for (int c = 0; c < kCH; ++c) { float d = x1[c] - m1; v1 += d * d; }
    v1 *= (1.f / kCH);
    float rs2 = rsqrtf(v1 + kEPS);
    float fx2[kCH];
    #pragma unroll
    for (int c = 0; c < kCH; ++c)
        fx2[c] = (x1[c] - m1) * rs2 * ln2_g[c] + ln2_b[c];

    float hgate[kCH];
    #pragma unroll
    for (int j = 0; j < kCH; ++j) {
        float e1 = 0.f, e2 = 0.f;
        #pragma unroll
        for (int c = 0; c < kCH; ++c) {
            e1 += fx2[c] * w_enc[j * kCH + c];
            e2 += fx2[c] * w_enc[(kCH + j) * kCH + c];
        }
        hgate[j] = e1 * gelu_exact(e2);
    }
    float x2v[kCH];
    #pragma unroll
    for (int c = 0; c < kCH; ++c) {
        float acc = fx2[c];
        #pragma unroll
        for (int j = 0; j < kCH; ++j) acc += hgate[j] * w_dec[c * kCH + j];
        x2v[c] = acc;
    }
    int b = n >> 8, rem = n & 255;
    #pragma unroll
    for (int c = 0; c < kCH; ++c) {
        float acc = b_out[c];
        #pragma unroll
        for (int j = 0; j < kCH; ++j) acc += x2v[j] * w_out[c * kCH + j];
        yd[(b * kCH + c) * 256 + rem] = acc;   // yd[b][c][i][k] layout
    }
}

// ---------------------------------------------------------------------------
// K3: bilinear upsample 16x16 -> 480x640 per (b,ch).
// Grid (10 chunks, 256 images) x 320 threads. Thread = (half in {0,1} of the
// 48-row chunk, cw in [0,160) = fixed float4 column group). x-interp weights
// A/B/C and the <=3 source rows a 24-row half touches are folded into
// registers ONCE; the 24-store steady-state loop is pure VALU + stores (no
// LDS). Wave = 64 consecutive cw -> 1024B coalesced stores. Writes 315 MB.
// ---------------------------------------------------------------------------
__global__ __launch_bounds__(320) void k_up(const float* __restrict__ yd,
                                            float* __restrict__ out) {
    const int chunk = blockIdx.x;           // [0,10) -> rows [chunk*48, +48)
    const int bc    = blockIdx.y;           // b*16 + c
    __shared__ float g[256];                // 16x16 source tile
    int tid = threadIdx.x;
    if (tid < 256) g[tid] = yd[bc * 256 + tid];
    __syncthreads();

    const int half = tid / 160;             // 0/1: rows [h0, h0+24)
    const int cw   = tid - half * 160;      // float4 column [0,160)
    const int h0   = chunk * 48 + half * 24;
    const float sy = 15.0f / 479.0f;
    const float sx = 15.0f / 639.0f;

    // --- per-thread x-interp weights (fixed): out_j = A*g[xa] + B*g[xa+1] + C*g[xc2]
    const int px = cw * 4;
    int xa = (int)((float)px * sx);
    if (xa > 14) xa = 14;
    float A[4], Bv[4], Cv[4];
    #pragma unroll
    for (int j = 0; j < 4; ++j) {
        float rx = (float)(px + j) * sx;
        int x0 = (int)rx; if (x0 > 15) x0 = 15;
        float wx = rx - (float)x0;
        int x1 = min(x0 + 1, 15);
        int r0 = x0 - xa;                   // 0 or 1
        int r1 = x1 - xa;                   // 0,1,2
        A[j] = 0.f; Bv[j] = 0.f; Cv[j] = 0.f;
        float w0 = 1.f - wx;
        if (r0 == 0) A[j] += w0; else Bv[j] += w0;
        if (r1 == 1) Bv[j] += wx; else if (r1 == 2) Cv[j] += wx; else A[j] += wx;
    }

    // --- horizontal pre-interp of the 3 source rows this half can touch
    const int ybase = (int)((float)h0 * sy);
    const int ya1 = min(ybase + 1, 15);
    const int ya2 = min(ybase + 2, 15);
    const int xc2 = min(xa + 2, 15);
    float hr0[4], hr1[4], hr2[4];
    {
        float a0 = g[ybase * 16 + xa], b0 = g[ybase * 16 + xa + 1], c0 = g[ybase * 16 + xc2];
        float a1 = g[ya1   * 16 + xa], b1 = g[ya1   * 16 + xa + 1], c1 = g[ya1   * 16 + xc2];
        float a2 = g[ya2   * 16 + xa], b2 = g[ya2   * 16 + xa + 1], c2 = g[ya2   * 16 + xc2];
        #pragma unroll
        for (int j = 0; j < 4; ++j) {
            hr0[j] = A[j] * a0 + Bv[j] * b0 + Cv[j] * c0;
            hr1[j] = A[j] * a1 + Bv[j] * b1 + Cv[j] * c1;
            hr2[j] = A[j] * a2 + Bv[j] * b2 + Cv[j] * c2;
        }
    }

    float4* dst = (float4*)(out + (size_t)bc * (kH * kW));
    #pragma unroll 4
    for (int r = 0; r < 24; ++r) {
        int ho = h0 + r;
        float ry = (float)ho * sy;
        int y0 = (int)ry;
        float wy = ry - (float)y0;
        bool up = (y0 > ybase);
        float4 res;
        #pragma unroll
        for (int j = 0; j < 4; ++j) {
            float top = up ? hr1[j] : hr0[j];
            float bot = up ? hr2[j] : hr1[j];
            ((float*)&res)[j] = top + (bot - top) * wy;
        }
        dst[ho * 160 + cw] = res;
    }
}

extern "C" void kernel_launch(void* const* d_in, const int* in_sizes, int n_in,
                              void* d_out, int out_size, void* d_ws, size_t ws_size,
                              hipStream_t stream) {
    const float* x     = (const float*)d_in[0];
    const float* w_in  = (const float*)d_in[1];
    const float* b_in  = (const float*)d_in[2];
    const float* ln1_g = (const float*)d_in[3];
    const float* ln1_b = (const float*)d_in[4];
    const float* Lre   = (const float*)d_in[5];
    const float* Lim   = (const float*)d_in[6];
    const float* Bre   = (const float*)d_in[7];
    const float* Bim   = (const float*)d_in[8];
    const float* Cre   = (const float*)d_in[9];
    const float* Cim   = (const float*)d_in[10];
    const float* Dv    = (const float*)d_in[11];
    const float* lstep = (const float*)d_in[12];
    const float* ln2_g = (const float*)d_in[13];
    const float* ln2_b = (const float*)d_in[14];
    const float* w_enc = (const float*)d_in[15];
    const float* w_dec = (const float*)d_in[16];
    const float* w_out = (const float*)d_in[17];
    const float* b_out = (const float*)d_in[18];

    float* seq = (float*)d_ws;          // kT*kN      = 61440 floats
    float* yd  = seq + kT * kN;         // kB*kCH*256 = 65536 floats
    float* out = (float*)d_out;

    k_down<<<kB * kT * 16, 320, 0, stream>>>(x, seq);
    k_ssm<<<kN / 64, 64, 0, stream>>>(seq, w_in, b_in, ln1_g, ln1_b, Lre, Lim,
                                      Bre, Bim, Cre, Cim, Dv, lstep, ln2_g, ln2_b,
                                      w_enc, w_dec, w_out, b_out, yd);
    k_up<<<dim3(10, kB * kCH), 320, 0, stream>>>(yd, out);
}

// Round 5
// 145.477 us; speedup vs baseline: 1.2493x; 1.2493x over previous
//
#include <hip/hip_runtime.h>
#include <math.h>

static constexpr int kB  = 16;
static constexpr int kT  = 15;
static constexpr int kH  = 480;
static constexpr int kW  = 640;
static constexpr int kCH = 16;
static constexpr int kP  = 8;
static constexpr float kEPS = 1e-5f;

__device__ __forceinline__ float gelu_exact(float v) {
    return 0.5f * v * (1.0f + erff(v * 0.7071067811865476f));
}

// ---------------------------------------------------------------------------
// K1: fused downsample + SSM scan + last-step head. One block per (b,i):
// streams 15 frames x 30 rows x 640 cols (1.15 MB, coalesced float4),
// reduces to seq[15][16] in LDS, runs 16 scans pole-parallel (128 thr),
// then the head channel-parallel (256 thr, shuffle LN2, transposed weights).
// ---------------------------------------------------------------------------
__global__ __launch_bounds__(640) void k_front(
    const float* __restrict__ x,
    const float* __restrict__ w_in, const float* __restrict__ b_in,
    const float* __restrict__ ln1_g, const float* __restrict__ ln1_b,
    const float* __restrict__ Lam_re, const float* __restrict__ Lam_im,
    const float* __restrict__ Bre, const float* __restrict__ Bim,
    const float* __restrict__ Cre, const float* __restrict__ Cim,
    const float* __restrict__ Dv, const float* __restrict__ log_step,
    const float* __restrict__ ln2_g, const float* __restrict__ ln2_b,
    const float* __restrict__ w_enc, const float* __restrict__ w_dec,
    const float* __restrict__ w_out, const float* __restrict__ b_out,
    float* __restrict__ yd)
{
    __shared__ float colsum[4 * 640];
    __shared__ float seqL[kT * 16];
    __shared__ float xsr[128], xsi[128];
    __shared__ float f2s[256], hgs[256], x2s[256];
    __shared__ float wencT[512], wdecT[256], woutT[256];
    __shared__ float boS[16], dvS[16], g2S[16], b2S[16];
    __shared__ float cav[16], cdv[16], cg1[16], cb1[16], cag[16], cdg[16];
    __shared__ float cLr[8], cLi[8], c1r[8], c1i[8], c0r[8], c0i[8],
                     cbr[8], cbi[8], cmk[8], cst[4];
    __shared__ float cmrT[128], cmiT[128];

    const int tid = threadIdx.x;
    const int b = blockIdx.x >> 4;
    const int i = blockIdx.x & 15;

    // ---- weight staging (transposed for conflict-free reads) ----
    if (tid < 512) wencT[(tid & 15) * 32 + (tid >> 4)] = w_enc[tid];
    if (tid < 256) {
        int jj = tid >> 4, cc = tid & 15;
        wdecT[tid] = w_dec[cc * 16 + jj];     // wdecT[j*16+c] = w_dec[c][j]
        woutT[tid] = w_out[cc * 16 + jj];     // woutT[j*16+c] = w_out[c][j]
    }
    if (tid < 16) {
        boS[tid] = b_out[tid]; dvS[tid] = Dv[tid];
        g2S[tid] = ln2_g[tid]; b2S[tid] = ln2_b[tid];
    }
    // ---- const build step 1 (on spare threads) ----
    if (tid >= 544 && tid < 560) {
        int c = tid - 544;
        float mw = 0.f, mb = 0.f;
        #pragma unroll
        for (int k = 0; k < kCH; ++k) { mw += w_in[k]; mb += b_in[k]; }
        mw *= (1.f / kCH); mb *= (1.f / kCH);
        float av = w_in[c] - mw, dv = b_in[c] - mb;
        float g = ln1_g[c], bb = ln1_b[c];
        cav[c] = av; cdv[c] = dv; cg1[c] = g; cb1[c] = bb;
        cag[c] = av * g; cdg[c] = dv * g;
    } else if (tid >= 560 && tid < 568) {
        int p = tid - 560;
        float st  = expf(log_step[p]);
        float lre = Lam_re[p], lim = Lam_im[p];
        float eL  = expf(lre * st);
        cLr[p] = eL * cosf(lim * st);
        cLi[p] = eL * sinf(lim * st);
        float freq = st * fabsf(lim) * 0.15915494309189535f;
        cmk[p] = (freq < 0.25f) ? 1.f : 0.f;
    }
    __syncthreads();
    // ---- const build step 2 ----
    if (tid < 8) {
        int p = tid;
        float lre = Lam_re[p], lim = Lam_im[p];
        float inv = 1.f / (lre * lre + lim * lim);
        float nr = cLr[p] - 1.f, ni = cLi[p];
        float qr = (nr * lre + ni * lim) * inv;
        float qi = (ni * lre - nr * lim) * inv;
        float s1r = 0.f, s1i = 0.f, s0r = 0.f, s0i = 0.f, sbr = 0.f, sbi = 0.f;
        #pragma unroll
        for (int c = 0; c < kCH; ++c) {
            float br = Bre[p * kCH + c], bi = Bim[p * kCH + c];
            s1r += cag[c] * br;  s1i += cag[c] * bi;
            s0r += cdg[c] * br;  s0i += cdg[c] * bi;
            sbr += cb1[c] * br;  sbi += cb1[c] * bi;
        }
        c1r[p] = qr * s1r - qi * s1i;  c1i[p] = qr * s1i + qi * s1r;
        c0r[p] = qr * s0r - qi * s0i;  c0i[p] = qr * s0i + qi * s0r;
        cbr[p] = qr * sbr - qi * sbi;  cbi[p] = qr * sbi + qi * sbr;
    } else if (tid == 8) {
        float Saa = 0.f, Sad = 0.f, Sdd = 0.f;
        #pragma unroll
        for (int c = 0; c < kCH; ++c) {
            Saa += cav[c] * cav[c];
            Sad += cav[c] * cdv[c];
            Sdd += cdv[c] * cdv[c];
        }
        cst[0] = Saa * (1.f / kCH);
        cst[1] = Sad * (1.f / kCH);
        cst[2] = Sdd * (1.f / kCH);
    } else if (tid >= 64 && tid < 192) {
        int idx = tid - 64;               // p*16 + c
        int p = idx >> 4, c = idx & 15;
        cmrT[idx] = Cre[c * kP + p] * cmk[p];
        cmiT[idx] = Cim[c * kP + p] * cmk[p];
    }

    // ---- streaming downsample: 2 outer iters x 4 t-pairs ----
    const int thalf = tid / 320;
    const int rem   = tid - thalf * 320;
    const int rhalf = rem / 160;
    const int col4  = rem - rhalf * 160;
    const size_t rowf4 = ((size_t)b * kT * kH + (size_t)i * 30 + rhalf * 15) * 160 + col4;
    const float4* __restrict__ xf4 = (const float4*)x;

    for (int o = 0; o < 2; ++o) {
        float acc[4];
        #pragma unroll
        for (int q = 0; q < 4; ++q) {
            acc[q] = 0.f;
            int t = (o * 4 + q) * 2 + thalf;
            if (t < kT) {
                const float4* s0 = xf4 + rowf4 + (size_t)t * (kH * 160);
                #pragma unroll
                for (int rr = 0; rr < 15; ++rr) {
                    float4 v = s0[rr * 160];
                    acc[q] += (v.x + v.y) + (v.z + v.w);
                }
            }
        }
        __syncthreads();                 // colsum free (prev reduce done)
        #pragma unroll
        for (int q = 0; q < 4; ++q) colsum[q * 640 + tid] = acc[q];
        __syncthreads();
        if (tid < 128) {
            int q = tid >> 5, r2 = tid & 31;
            int thf = r2 >> 4, k = r2 & 15;
            int t = (o * 4 + q) * 2 + thf;
            if (t < kT) {
                int base = q * 640 + thf * 320 + k * 10;
                float s = 0.f;
                #pragma unroll
                for (int j = 0; j < 10; ++j)
                    s += colsum[base + j] + colsum[base + 160 + j];
                seqL[t * 16 + k] = s * (1.0f / 1200.0f);
            }
        }
    }
    __syncthreads();

    // ---- SSM scan, pole-parallel: thread = (k, p) ----
    if (tid < 128) {
        int k = tid >> 3, p = tid & 7;
        float Lr = cLr[p], Li = cLi[p];
        float a1r = c1r[p], a1i = c1i[p], a0r = c0r[p], a0i = c0i[p];
        float abr = cbr[p], abi = cbi[p];
        float Saa = cst[0], Sad = cst[1], Sdd = cst[2];
        float xr = 0.f, xi = 0.f;
        #pragma unroll
        for (int t = 0; t < kT; ++t) {
            float s = seqL[t * 16 + k];
            float r = rsqrtf(s * s * Saa + 2.f * s * Sad + Sdd + kEPS);
            float be = r * s;
            float bur = be * a1r + r * a0r + abr;
            float bui = be * a1i + r * a0i + abi;
            float nr = Lr * xr - Li * xi + bur;
            float ni = Lr * xi + Li * xr + bui;
            xr = nr; xi = ni;
        }
        xsr[k * 8 + p] = xr; xsi[k * 8 + p] = xi;
    }
    __syncthreads();

    // ---- head, channel-parallel: thread = (k, c) ----
    if (tid < 256) {
        int k = tid >> 4, c = tid & 15;
        float s = seqL[14 * 16 + k];
        float r = rsqrtf(s * s * cst[0] + 2.f * s * cst[1] + cst[2] + kEPS);
        float fx = (s * cav[c] + cdv[c]) * r * cg1[c] + cb1[c];
        float ys = fx * dvS[c];
        #pragma unroll
        for (int p = 0; p < kP; ++p)
            ys += xsr[k * 8 + p] * cmrT[p * 16 + c] - xsi[k * 8 + p] * cmiT[p * 16 + c];
        float x1 = gelu_exact(ys) + fx;
        // LN2 via 16-lane shuffle reduce
        float m = x1;
        m += __shfl_xor(m, 1); m += __shfl_xor(m, 2);
        m += __shfl_xor(m, 4); m += __shfl_xor(m, 8);
        m *= (1.f / kCH);
        float d = x1 - m;
        float v = d * d;
        v += __shfl_xor(v, 1); v += __shfl_xor(v, 2);
        v += __shfl_xor(v, 4); v += __shfl_xor(v, 8);
        v *= (1.f / kCH);
        float rs2 = rsqrtf(v + kEPS);
        f2s[tid] = d * rs2 * g2S[c] + b2S[c];
    }
    __syncthreads();
    if (tid < 256) {
        int k = tid >> 4, j = tid & 15;
        float e1 = 0.f, e2 = 0.f;
        #pragma unroll
        for (int c = 0; c < kCH; ++c) {
            float f = f2s[k * 16 + c];
            e1 += f * wencT[c * 32 + j];
            e2 += f * wencT[c * 32 + 16 + j];
        }
        hgs[tid] = e1 * gelu_exact(e2);
    }
    __syncthreads();
    if (tid < 256) {
        int k = tid >> 4, c = tid & 15;
        float acc = f2s[tid];
        #pragma unroll
        for (int j = 0; j < kCH; ++j) acc += hgs[k * 16 + j] * wdecT[j * 16 + c];
        x2s[tid] = acc;
    }
    __syncthreads();
    if (tid < 256) {
        int k = tid >> 4, c = tid & 15;
        float acc = boS[c];
        #pragma unroll
        for (int j = 0; j < kCH; ++j) acc += x2s[k * 16 + j] * woutT[j * 16 + c];
        yd[(b * kCH + c) * 256 + i * 16 + k] = acc;
    }
}

// ---------------------------------------------------------------------------
// K2: bilinear upsample 16x16 -> 480x640 per (b,ch). Grid (10 chunks, 256
// images) x 320 threads; per-thread fixed 4-column group, x-weights folded
// once, steady-state loop is pure VALU + coalesced float4 stores (315 MB).
// ---------------------------------------------------------------------------
__global__ __launch_bounds__(320) void k_up(const float* __restrict__ yd,
                                            float* __restrict__ out) {
    const int chunk = blockIdx.x;           // [0,10) -> rows [chunk*48, +48)
    const int bc    = blockIdx.y;           // b*16 + c
    __shared__ float g[256];                // 16x16 source tile
    int tid = threadIdx.x;
    if (tid < 256) g[tid] = yd[bc * 256 + tid];
    __syncthreads();

    const int half = tid / 160;             // 0/1: rows [h0, h0+24)
    const int cw   = tid - half * 160;      // float4 column [0,160)
    const int h0   = chunk * 48 + half * 24;
    const float sy = 15.0f / 479.0f;
    const float sx = 15.0f / 639.0f;

    const int px = cw * 4;
    int xa = (int)((float)px * sx);
    if (xa > 14) xa = 14;
    const int xc2 = min(xa + 2, 15);
    float A[4], Bv[4], Cv[4];
    #pragma unroll
    for (int j = 0; j < 4; ++j) {
        float rx = (float)(px + j) * sx;
        int x0 = (int)rx; if (x0 > 15) x0 = 15;
        float wx = rx - (float)x0;
        int x1 = min(x0 + 1, 15);
        int r0 = x0 - xa;
        int r1 = x1 - xa;
        A[j] = 0.f; Bv[j] = 0.f; Cv[j] = 0.f;
        float w0 = 1.f - wx;
        if (r0 == 0) A[j] += w0; else Bv[j] += w0;
        if (r1 == 1) Bv[j] += wx; else if (r1 == 2) Cv[j] += wx; else A[j] += wx;
    }

    const int ybase = (int)((float)h0 * sy);
    const int ya1 = min(ybase + 1, 15);
    const int ya2 = min(ybase + 2, 15);
    float hr0[4], hr1[4], hr2[4];
    {
        float a0 = g[ybase * 16 + xa], b0 = g[ybase * 16 + xa + 1], c0 = g[ybase * 16 + xc2];
        float a1 = g[ya1   * 16 + xa], b1 = g[ya1   * 16 + xa + 1], c1 = g[ya1   * 16 + xc2];
        float a2 = g[ya2   * 16 + xa], b2 = g[ya2   * 16 + xa + 1], c2 = g[ya2   * 16 + xc2];
        #pragma unroll
        for (int j = 0; j < 4; ++j) {
            hr0[j] = A[j] * a0 + Bv[j] * b0 + Cv[j] * c0;
            hr1[j] = A[j] * a1 + Bv[j] * b1 + Cv[j] * c1;
            hr2[j] = A[j] * a2 + Bv[j] * b2 + Cv[j] * c2;
        }
    }

    float4* dst = (float4*)(out + (size_t)bc * (kH * kW));
    #pragma unroll 4
    for (int r = 0; r < 24; ++r) {
        int ho = h0 + r;
        float ry = (float)ho * sy;
        int y0 = (int)ry;
        float wy = ry - (float)y0;
        bool up = (y0 > ybase);
        float4 res;
        #pragma unroll
        for (int j = 0; j < 4; ++j) {
            float top = up ? hr1[j] : hr0[j];
            float bot = up ? hr2[j] : hr1[j];
            ((float*)&res)[j] = top + (bot - top) * wy;
        }
        dst[ho * 160 + cw] = res;
    }
}

extern "C" void kernel_launch(void* const* d_in, const int* in_sizes, int n_in,
                              void* d_out, int out_size, void* d_ws, size_t ws_size,
                              hipStream_t stream) {
    const float* x     = (const float*)d_in[0];
    const float* w_in  = (const float*)d_in[1];
    const float* b_in  = (const float*)d_in[2];
    const float* ln1_g = (const float*)d_in[3];
    const float* ln1_b = (const float*)d_in[4];
    const float* Lre   = (const float*)d_in[5];
    const float* Lim   = (const float*)d_in[6];
    const float* Bre   = (const float*)d_in[7];
    const float* Bim   = (const float*)d_in[8];
    const float* Cre   = (const float*)d_in[9];
    const float* Cim   = (const float*)d_in[10];
    const float* Dv    = (const float*)d_in[11];
    const float* lstep = (const float*)d_in[12];
    const float* ln2_g = (const float*)d_in[13];
    const float* ln2_b = (const float*)d_in[14];
    const float* w_enc = (const float*)d_in[15];
    const float* w_dec = (const float*)d_in[16];
    const float* w_out = (const float*)d_in[17];
    const float* b_out = (const float*)d_in[18];

    float* yd  = (float*)d_ws;          // kB*kCH*256 = 65536 floats
    float* out = (float*)d_out;

    k_front<<<kB * 16, 640, 0, stream>>>(x, w_in, b_in, ln1_g, ln1_b, Lre, Lim,
                                         Bre, Bim, Cre, Cim, Dv, lstep, ln2_g,
                                         ln2_b, w_enc, w_dec, w_out, b_out, yd);
    k_up<<<dim3(10, kB * kCH), 320, 0, stream>>>(yd, out);
}